// Round 1
// baseline (976.531 us; speedup 1.0000x reference)
//
#include <hip/hip_runtime.h>
#include <hip/hip_bf16.h>

// Problem constants (B=256, T=512, D=512, H=64)
#define BB 256
#define TT 512
#define DD 512
#define HH 64
#define NG 256            // 4*H gates
#define MM (BB * TT)      // 131072 rows of x_proj

// ---------------------------------------------------------------------------
// Phase 1: x_proj[m, g] = sum_k X[m,k] * W_ih[g,k] + (b_ih[g] + b_hh[g])
// fp32 tiled GEMM, 128x128 tile, K-chunk 8, 8x8 outputs per thread
// (split as 2x2 blocks of 4x4 at +0/+64 offsets to keep LDS reads 2-way max)
// ---------------------------------------------------------------------------
__global__ __launch_bounds__(256) void gemm_xproj(
    const float* __restrict__ X,     // [MM, DD]
    const float* __restrict__ W,     // [NG, DD]
    const float* __restrict__ b_ih,  // [NG]
    const float* __restrict__ b_hh,  // [NG]
    float* __restrict__ XP)          // [MM, NG]
{
    __shared__ float As[8][128];
    __shared__ float Bs[8][128];

    const int tid   = threadIdx.x;
    const int m_blk = blockIdx.x * 128;
    const int n_blk = blockIdx.y * 128;

    const int lr = tid >> 1;         // 0..127: tile row loaded by this thread
    const int lk = (tid & 1) * 4;    // 0 or 4: k sub-offset

    const float* xg = X + (size_t)(m_blk + lr) * DD + lk;
    const float* wg = W + (size_t)(n_blk + lr) * DD + lk;

    const int m0 = (tid & 15) * 4;   // 0..60
    const int n0 = (tid >> 4) * 4;   // 0..60

    // per-column bias (reused across all rows)
    float bias[2][4];
#pragma unroll
    for (int nh = 0; nh < 2; ++nh) {
        int cn = n_blk + n0 + nh * 64;
#pragma unroll
        for (int j = 0; j < 4; ++j)
            bias[nh][j] = b_ih[cn + j] + b_hh[cn + j];
    }

    float acc[2][2][4][4];
#pragma unroll
    for (int a = 0; a < 2; ++a)
#pragma unroll
        for (int b = 0; b < 2; ++b)
#pragma unroll
            for (int i = 0; i < 4; ++i)
#pragma unroll
                for (int j = 0; j < 4; ++j) acc[a][b][i][j] = 0.f;

    for (int kb = 0; kb < DD; kb += 8) {
        float4 xa = *(const float4*)(xg + kb);
        float4 wb = *(const float4*)(wg + kb);
        __syncthreads();   // previous tile fully consumed before overwrite
        As[lk + 0][lr] = xa.x; As[lk + 1][lr] = xa.y;
        As[lk + 2][lr] = xa.z; As[lk + 3][lr] = xa.w;
        Bs[lk + 0][lr] = wb.x; Bs[lk + 1][lr] = wb.y;
        Bs[lk + 2][lr] = wb.z; Bs[lk + 3][lr] = wb.w;
        __syncthreads();
#pragma unroll
        for (int k = 0; k < 8; ++k) {
            float4 a0 = *(const float4*)&As[k][m0];
            float4 a1 = *(const float4*)&As[k][m0 + 64];
            float4 b0 = *(const float4*)&Bs[k][n0];
            float4 b1 = *(const float4*)&Bs[k][n0 + 64];
            float am[2][4] = {{a0.x, a0.y, a0.z, a0.w}, {a1.x, a1.y, a1.z, a1.w}};
            float bn[2][4] = {{b0.x, b0.y, b0.z, b0.w}, {b1.x, b1.y, b1.z, b1.w}};
#pragma unroll
            for (int mh = 0; mh < 2; ++mh)
#pragma unroll
                for (int nh = 0; nh < 2; ++nh)
#pragma unroll
                    for (int i = 0; i < 4; ++i)
#pragma unroll
                        for (int j = 0; j < 4; ++j)
                            acc[mh][nh][i][j] += am[mh][i] * bn[nh][j];
        }
    }

    // epilogue: add bias, store
#pragma unroll
    for (int mh = 0; mh < 2; ++mh) {
#pragma unroll
        for (int i = 0; i < 4; ++i) {
            int row = m_blk + m0 + mh * 64 + i;
            float* orow = XP + (size_t)row * NG + n_blk;
#pragma unroll
            for (int nh = 0; nh < 2; ++nh) {
                float4 v;
                v.x = acc[mh][nh][i][0] + bias[nh][0];
                v.y = acc[mh][nh][i][1] + bias[nh][1];
                v.z = acc[mh][nh][i][2] + bias[nh][2];
                v.w = acc[mh][nh][i][3] + bias[nh][3];
                *(float4*)(orow + n0 + nh * 64) = v;
            }
        }
    }
}

// ---------------------------------------------------------------------------
// Phase 2: LSTM recurrence, 1 batch per workgroup (256 WGs = 1/CU),
// 1 thread per gate. W_hh row cached in 64 VGPRs; h broadcast via LDS.
// Wave g/64: 0 -> i(sigmoid), 1 -> f(sigmoid), 2 -> g(tanh), 3 -> o(sigmoid)
// => activation branch is wave-uniform.
// ---------------------------------------------------------------------------
__global__ __launch_bounds__(256) void lstm_rec(
    const float* __restrict__ XP,   // [BB, TT, NG]
    const float* __restrict__ Whh,  // [NG, HH]
    float* __restrict__ pooled)     // [BB, HH]
{
    const int b = blockIdx.x;
    const int g = threadIdx.x;      // gate index 0..255

    float w[HH];
    const float4* wg4 = (const float4*)(Whh + (size_t)g * HH);
#pragma unroll
    for (int q = 0; q < HH / 4; ++q) ((float4*)w)[q] = wg4[q];

    __shared__ float h_s[HH];
    __shared__ float gates_s[NG];

    float c = 0.f, hsum = 0.f;
    if (g < HH) h_s[g] = 0.f;
    __syncthreads();

    const float* xp = XP + (size_t)b * TT * NG;
    float xnext = xp[g];   // prefetch t=0

    for (int t = 0; t < TT; ++t) {
        float acc = xnext;
        if (t + 1 < TT) xnext = xp[(size_t)(t + 1) * NG + g];

        const float4* h4 = (const float4*)h_s;
#pragma unroll
        for (int q = 0; q < HH / 4; ++q) {
            float4 hv = h4[q];
            acc += w[4 * q + 0] * hv.x;
            acc += w[4 * q + 1] * hv.y;
            acc += w[4 * q + 2] * hv.z;
            acc += w[4 * q + 3] * hv.w;
        }

        float act;
        if (g < 128 || g >= 192) {
            act = 1.f / (1.f + __expf(-acc));            // sigmoid (i, f, o)
        } else {
            float s = 1.f / (1.f + __expf(-2.f * acc));  // tanh via sigmoid
            act = 2.f * s - 1.f;
        }
        gates_s[g] = act;
        __syncthreads();

        if (g < HH) {
            float iv = gates_s[g];
            float fv = gates_s[HH + g];
            float gv = gates_s[2 * HH + g];
            float ov = gates_s[3 * HH + g];
            c = fv * c + iv * gv;
            float s2 = 1.f / (1.f + __expf(-2.f * c));
            float h = ov * (2.f * s2 - 1.f);
            hsum += h;
            h_s[g] = h;
        }
        __syncthreads();
    }

    if (g < HH) pooled[(size_t)b * HH + g] = hsum * (1.0f / (float)TT);
}

// ---------------------------------------------------------------------------
// Phase 3: MLP head + softmax. One block, one thread per batch row.
// ---------------------------------------------------------------------------
__global__ __launch_bounds__(256) void head_kernel(
    const float* __restrict__ pooled,  // [BB, HH]
    const float* __restrict__ W1,      // [32, HH]
    const float* __restrict__ b1,      // [32]
    const float* __restrict__ W2,      // [3, 32]
    const float* __restrict__ b2,      // [3]
    float* __restrict__ out)           // [BB, 3]
{
    __shared__ float W1s[32 * HH];
    __shared__ float W2s[3 * 32];
    __shared__ float b1s[32];
    __shared__ float b2s[3];

    const int tid = threadIdx.x;
    for (int i = tid; i < 32 * HH; i += 256) W1s[i] = W1[i];
    if (tid < 96) W2s[tid] = W2[tid];
    if (tid < 32) b1s[tid] = b1[tid];
    if (tid < 3)  b2s[tid] = b2[tid];
    __syncthreads();

    float p[HH];
    const float4* p4 = (const float4*)(pooled + (size_t)tid * HH);
#pragma unroll
    for (int q = 0; q < HH / 4; ++q) ((float4*)p)[q] = p4[q];

    float hbuf[32];
#pragma unroll
    for (int k = 0; k < 32; ++k) {
        float s = b1s[k];
        const float* wr = &W1s[k * HH];
#pragma unroll
        for (int j = 0; j < HH; ++j) s += p[j] * wr[j];
        hbuf[k] = s > 0.f ? s : 0.f;
    }

    float lg[3];
#pragma unroll
    for (int cc = 0; cc < 3; ++cc) {
        float s = b2s[cc];
        const float* wr = &W2s[cc * 32];
#pragma unroll
        for (int k = 0; k < 32; ++k) s += hbuf[k] * wr[k];
        lg[cc] = s;
    }

    float mx = fmaxf(lg[0], fmaxf(lg[1], lg[2]));
    float e0 = __expf(lg[0] - mx);
    float e1 = __expf(lg[1] - mx);
    float e2 = __expf(lg[2] - mx);
    float inv = 1.f / (e0 + e1 + e2);
    out[tid * 3 + 0] = e0 * inv;
    out[tid * 3 + 1] = e1 * inv;
    out[tid * 3 + 2] = e2 * inv;
}

// ---------------------------------------------------------------------------
extern "C" void kernel_launch(void* const* d_in, const int* in_sizes, int n_in,
                              void* d_out, int out_size, void* d_ws, size_t ws_size,
                              hipStream_t stream) {
    const float* x    = (const float*)d_in[0];  // [256,512,512]
    const float* W_ih = (const float*)d_in[1];  // [256,512]
    const float* W_hh = (const float*)d_in[2];  // [256,64]
    const float* b_ih = (const float*)d_in[3];  // [256]
    const float* b_hh = (const float*)d_in[4];  // [256]
    const float* W1   = (const float*)d_in[5];  // [32,64]
    const float* b1   = (const float*)d_in[6];  // [32]
    const float* W2   = (const float*)d_in[7];  // [3,32]
    const float* b2   = (const float*)d_in[8];  // [3]
    float* out = (float*)d_out;

    // workspace layout: XP [MM*NG] fp32 (128 MiB), then pooled [BB*HH]
    float* XP     = (float*)d_ws;
    float* pooled = XP + (size_t)MM * NG;

    gemm_xproj<<<dim3(MM / 128, NG / 128), 256, 0, stream>>>(x, W_ih, b_ih, b_hh, XP);
    lstm_rec<<<dim3(BB), 256, 0, stream>>>(XP, W_hh, pooled);
    head_kernel<<<dim3(1), 256, 0, stream>>>(pooled, W1, b1, W2, b2, out);
}

// Round 2
// 917.477 us; speedup vs baseline: 1.0644x; 1.0644x over previous
//
#include <hip/hip_runtime.h>
#include <hip/hip_bf16.h>

// Problem constants (B=256, T=512, D=512, H=64)
#define BB 256
#define TT 512
#define DD 512
#define HH 64
#define NG 256            // 4*H gates
#define MM (BB * TT)      // 131072 rows of x_proj

// GEMM tiling
#define BM 128
#define BN 256
#define BK 32
#define LDA 40            // padded LDS row stride in elements (80B: 16B-aligned, <=2-way banks)
#define LDB 40

typedef short short8 __attribute__((ext_vector_type(8)));
typedef float f32x4 __attribute__((ext_vector_type(4)));

// fp32x4 -> packed 4x bf16 (RNE) as a 64-bit value
__device__ inline unsigned long long pack4bf16(float4 v) {
    __hip_bfloat162 lo = __float22bfloat162_rn(make_float2(v.x, v.y));
    __hip_bfloat162 hi = __float22bfloat162_rn(make_float2(v.z, v.w));
    unsigned lu, hu;
    __builtin_memcpy(&lu, &lo, 4);
    __builtin_memcpy(&hu, &hi, 4);
    return ((unsigned long long)hu << 32) | lu;
}

// ---------------------------------------------------------------------------
// Phase 1: XP[m,g] = X[m,:] . W_ih[g,:] + (b_ih[g]+b_hh[g])
// bf16 MFMA GEMM, BM=128 x BN=256 (full N per block -> X read once), BK=32.
// fp32 inputs converted to bf16 during LDS staging; fp32 accumulate.
// 4 waves in 2x2; each wave: 64x128 C-region = 4 M-tiles x 8 N-tiles of 16x16.
// ---------------------------------------------------------------------------
__global__ __launch_bounds__(256, 2) void gemm_xproj(
    const float* __restrict__ X,     // [MM, DD]
    const float* __restrict__ W,     // [NG, DD]
    const float* __restrict__ b_ih,  // [NG]
    const float* __restrict__ b_hh,  // [NG]
    float* __restrict__ XP)          // [MM, NG]
{
    __shared__ unsigned short As[BM * LDA];   // 10240 B
    __shared__ unsigned short Bs[BN * LDB];   // 20480 B
    __shared__ float bias_s[NG];

    const int tid   = threadIdx.x;
    const int m_blk = blockIdx.x * BM;
    const int lane  = tid & 63;
    const int wv    = tid >> 6;      // wave 0..3
    const int wm    = wv & 1;        // M half (64 rows)
    const int wn    = wv >> 1;       // N half (128 cols)
    const int q     = lane >> 4;     // k-quad for MFMA frags
    const int cnn   = lane & 15;

    bias_s[tid] = b_ih[tid] + b_hh[tid];

    f32x4 acc[4][8];
#pragma unroll
    for (int i = 0; i < 4; ++i)
#pragma unroll
        for (int j = 0; j < 8; ++j) acc[i][j] = (f32x4)0.f;

    for (int kc = 0; kc < DD / BK; ++kc) {
        const int kof = kc * BK;

        // global loads (fp32), issued before the barrier to overlap prev compute
        float4 av[4], bv[8];
#pragma unroll
        for (int u = 0; u < 4; ++u) {            // A: 128 rows x 8 chunks of 16B
            int c = tid + 256 * u;               // chunk id 0..1023
            av[u] = *(const float4*)(X + (size_t)(m_blk + (c >> 3)) * DD + kof + (c & 7) * 4);
        }
#pragma unroll
        for (int u = 0; u < 8; ++u) {            // B: 256 rows x 8 chunks of 16B
            int c = tid + 256 * u;               // chunk id 0..2047
            bv[u] = *(const float4*)(W + (size_t)(c >> 3) * DD + kof + (c & 7) * 4);
        }

        __syncthreads();   // previous tile fully consumed
#pragma unroll
        for (int u = 0; u < 4; ++u) {
            int c = tid + 256 * u;
            *(unsigned long long*)&As[(c >> 3) * LDA + (c & 7) * 4] = pack4bf16(av[u]);
        }
#pragma unroll
        for (int u = 0; u < 8; ++u) {
            int c = tid + 256 * u;
            *(unsigned long long*)&Bs[(c >> 3) * LDB + (c & 7) * 4] = pack4bf16(bv[u]);
        }
        __syncthreads();

        // LDS -> MFMA fragments (A[m][k], B[n][k]; lane&15 = m/n, quad*8 = k)
        short8 af[4], bf[8];
#pragma unroll
        for (int i = 0; i < 4; ++i)
            af[i] = *(const short8*)&As[(wm * 64 + i * 16 + cnn) * LDA + q * 8];
#pragma unroll
        for (int j = 0; j < 8; ++j)
            bf[j] = *(const short8*)&Bs[(wn * 128 + j * 16 + cnn) * LDB + q * 8];

#pragma unroll
        for (int i = 0; i < 4; ++i)
#pragma unroll
            for (int j = 0; j < 8; ++j)
                acc[i][j] = __builtin_amdgcn_mfma_f32_16x16x32_bf16(af[i], bf[j], acc[i][j], 0, 0, 0);
    }

    // epilogue: C/D layout col = lane&15 (n), row = quad*4 + reg (m)
#pragma unroll
    for (int j = 0; j < 8; ++j) {
        const int n  = wn * 128 + j * 16 + cnn;
        const float bvv = bias_s[n];
#pragma unroll
        for (int i = 0; i < 4; ++i) {
            const int m0 = m_blk + wm * 64 + i * 16 + q * 4;
#pragma unroll
            for (int r = 0; r < 4; ++r)
                XP[(size_t)(m0 + r) * NG + n] = acc[i][j][r] + bvv;
        }
    }
}

// ---------------------------------------------------------------------------
// Phase 2: LSTM recurrence. 1 batch per block (256 blocks = 1/CU).
// Thread tid = gate index; wave wv = gate type (0:i 1:f 2:g 3:o) -> uniform
// activation. Every wave keeps the FULL h (lane j holds h_j) and redundantly
// computes the c/h update, so the h.Whh dot is pure readlane+FMA (no LDS).
// Gate exchange via double-buffered LDS, ONE barrier per step.
// ---------------------------------------------------------------------------
__global__ __launch_bounds__(256) void lstm_rec(
    const float* __restrict__ XP,   // [BB, TT, NG]
    const float* __restrict__ Whh,  // [NG, HH]
    float* __restrict__ pooled)     // [BB, HH]
{
    const int b   = blockIdx.x;
    const int tid = threadIdx.x;
    const int wv  = tid >> 6;
    const int j   = tid & 63;

    float wrow[HH];
#pragma unroll
    for (int u = 0; u < HH / 4; ++u)
        ((float4*)wrow)[u] = ((const float4*)(Whh + (size_t)tid * HH))[u];

    __shared__ float gbuf[2][NG];

    float h = 0.f, c = 0.f, hsum = 0.f;
    const float* xp = XP + (size_t)b * TT * NG + tid;

    // prefetch ring, depth 4 (covers ~900cyc HBM latency at ~350cyc/step)
    float xr[4];
#pragma unroll
    for (int u = 0; u < 4; ++u) xr[u] = xp[(size_t)u * NG];

    for (int t0 = 0; t0 < TT; t0 += 4) {
#pragma unroll
        for (int u = 0; u < 4; ++u) {
            const int t = t0 + u;
            float acc = xr[u];
            if (t + 4 < TT) xr[u] = xp[(size_t)(t + 4) * NG];

            const int hb = __float_as_int(h);
#pragma unroll
            for (int k = 0; k < HH; ++k) {
                float hk = __int_as_float(__builtin_amdgcn_readlane(hb, k));
                acc = fmaf(wrow[k], hk, acc);
            }

            float a;
            if (wv == 2) {                          // tanh gate (wave-uniform)
                float e = __expf(-2.f * acc);
                a = 2.f / (1.f + e) - 1.f;
            } else {                                // sigmoid gates
                a = 1.f / (1.f + __expf(-acc));
            }
            const int p = t & 1;
            gbuf[p][tid] = a;
            __syncthreads();
            const float iv = gbuf[p][j];
            const float fv = gbuf[p][64 + j];
            const float gv = gbuf[p][128 + j];
            const float ov = gbuf[p][192 + j];
            c = fv * c + iv * gv;
            const float e2 = __expf(-2.f * c);
            const float th = 2.f / (1.f + e2) - 1.f;
            h = ov * th;
            hsum += h;
        }
    }

    if (tid < HH) pooled[(size_t)b * HH + j] = hsum * (1.f / (float)TT);
}

// ---------------------------------------------------------------------------
// Phase 3: MLP head + softmax. One block, one thread per batch row.
// ---------------------------------------------------------------------------
__global__ __launch_bounds__(256) void head_kernel(
    const float* __restrict__ pooled,  // [BB, HH]
    const float* __restrict__ W1,      // [32, HH]
    const float* __restrict__ b1,      // [32]
    const float* __restrict__ W2,      // [3, 32]
    const float* __restrict__ b2,      // [3]
    float* __restrict__ out)           // [BB, 3]
{
    __shared__ float W1s[32 * HH];
    __shared__ float W2s[3 * 32];
    __shared__ float b1s[32];
    __shared__ float b2s[3];

    const int tid = threadIdx.x;
    for (int i = tid; i < 32 * HH; i += 256) W1s[i] = W1[i];
    if (tid < 96) W2s[tid] = W2[tid];
    if (tid < 32) b1s[tid] = b1[tid];
    if (tid < 3)  b2s[tid] = b2[tid];
    __syncthreads();

    float p[HH];
    const float4* p4 = (const float4*)(pooled + (size_t)tid * HH);
#pragma unroll
    for (int q = 0; q < HH / 4; ++q) ((float4*)p)[q] = p4[q];

    float hbuf[32];
#pragma unroll
    for (int k = 0; k < 32; ++k) {
        float s = b1s[k];
        const float* wr = &W1s[k * HH];
#pragma unroll
        for (int jj = 0; jj < HH; ++jj) s += p[jj] * wr[jj];
        hbuf[k] = s > 0.f ? s : 0.f;
    }

    float lg[3];
#pragma unroll
    for (int cc = 0; cc < 3; ++cc) {
        float s = b2s[cc];
        const float* wr = &W2s[cc * 32];
#pragma unroll
        for (int k = 0; k < 32; ++k) s += hbuf[k] * wr[k];
        lg[cc] = s;
    }

    float mx = fmaxf(lg[0], fmaxf(lg[1], lg[2]));
    float e0 = __expf(lg[0] - mx);
    float e1 = __expf(lg[1] - mx);
    float e2 = __expf(lg[2] - mx);
    float inv = 1.f / (e0 + e1 + e2);
    out[tid * 3 + 0] = e0 * inv;
    out[tid * 3 + 1] = e1 * inv;
    out[tid * 3 + 2] = e2 * inv;
}

// ---------------------------------------------------------------------------
extern "C" void kernel_launch(void* const* d_in, const int* in_sizes, int n_in,
                              void* d_out, int out_size, void* d_ws, size_t ws_size,
                              hipStream_t stream) {
    const float* x    = (const float*)d_in[0];  // [256,512,512]
    const float* W_ih = (const float*)d_in[1];  // [256,512]
    const float* W_hh = (const float*)d_in[2];  // [256,64]
    const float* b_ih = (const float*)d_in[3];  // [256]
    const float* b_hh = (const float*)d_in[4];  // [256]
    const float* W1   = (const float*)d_in[5];  // [32,64]
    const float* b1   = (const float*)d_in[6];  // [32]
    const float* W2   = (const float*)d_in[7];  // [3,32]
    const float* b2   = (const float*)d_in[8];  // [3]
    float* out = (float*)d_out;

    // workspace layout: XP [MM*NG] fp32 (128 MiB), then pooled [BB*HH]
    float* XP     = (float*)d_ws;
    float* pooled = XP + (size_t)MM * NG;

    gemm_xproj<<<dim3(MM / BM), 256, 0, stream>>>(x, W_ih, b_ih, b_hh, XP);
    lstm_rec<<<dim3(BB), 256, 0, stream>>>(XP, W_hh, pooled);
    head_kernel<<<dim3(1), 256, 0, stream>>>(pooled, W1, b1, W2, b2, out);
}

// Round 3
// 652.954 us; speedup vs baseline: 1.4956x; 1.4051x over previous
//
#include <hip/hip_runtime.h>
#include <hip/hip_bf16.h>

// Problem constants (B=256, T=512, D=512, H=64)
#define BB 256
#define TT 512
#define DD 512
#define HH 64
#define NG 256            // 4*H gates
#define MM (BB * TT)      // 131072 rows of x_proj

// GEMM tiling
#define BM 128
#define BN 256
#define BK 32
#define LDA 40            // padded LDS row stride (80B rows: 8B-aligned b64 ops, 2-way banks = free)
#define LDB 40
#define NKC (DD / BK)     // 16 K-chunks

typedef short short8 __attribute__((ext_vector_type(8)));
typedef short short4v __attribute__((ext_vector_type(4)));
typedef float f32x4 __attribute__((ext_vector_type(4)));

// fp32x4 -> packed 4x bf16 (RNE) as a 64-bit value
__device__ inline unsigned long long pack4bf16(float4 v) {
    __hip_bfloat162 lo = __float22bfloat162_rn(make_float2(v.x, v.y));
    __hip_bfloat162 hi = __float22bfloat162_rn(make_float2(v.z, v.w));
    unsigned lu, hu;
    __builtin_memcpy(&lu, &lo, 4);
    __builtin_memcpy(&hu, &hi, 4);
    return ((unsigned long long)hu << 32) | lu;
}

// ---------------------------------------------------------------------------
// Phase 1: XP[m,g] = X[m,:] . W_ih[g,:] + (b_ih[g]+b_hh[g])
// bf16 MFMA GEMM. 512 threads = 8 waves in 2x4; per-wave C = 64x64
// (acc = 64 VGPRs, vs 128 last round -> no spill). Double-buffered LDS,
// ONE barrier per K-iter; next tile's global loads issued a full iteration
// before their LDS-stage (latency hidden behind compute+barrier).
// ---------------------------------------------------------------------------
__global__ __launch_bounds__(512, 2) void gemm_xproj(
    const float* __restrict__ X,     // [MM, DD]
    const float* __restrict__ W,     // [NG, DD]
    const float* __restrict__ b_ih,  // [NG]
    const float* __restrict__ b_hh,  // [NG]
    float* __restrict__ XP)          // [MM, NG]
{
    __shared__ unsigned short As[2][BM * LDA];   // 2 x 10240 B
    __shared__ unsigned short Bs[2][BN * LDB];   // 2 x 20480 B
    __shared__ float bias_s[NG];

    const int tid   = threadIdx.x;
    const int m_blk = blockIdx.x * BM;
    const int lane  = tid & 63;
    const int wv    = tid >> 6;      // wave 0..7
    const int wm    = wv & 1;        // M half (64 rows)
    const int wn    = wv >> 1;       // N quarter (64 cols)
    const int q     = lane >> 4;     // k-quad
    const int cn    = lane & 15;

    if (tid < NG) bias_s[tid] = b_ih[tid] + b_hh[tid];

    f32x4 acc[4][4];
#pragma unroll
    for (int i = 0; i < 4; ++i)
#pragma unroll
        for (int j = 0; j < 4; ++j) acc[i][j] = (f32x4)0.f;

    float4 a_r[2], b_r[4];

    // tile-k loads: A 128x32 fp32 = 1024 float4 (2/thread), B 256x32 = 2048 (4/thread)
#define LOAD_TILE(KC)                                                                     \
    do {                                                                                  \
        const int kof = (KC) * BK;                                                        \
        _Pragma("unroll")                                                                 \
        for (int u = 0; u < 2; ++u) {                                                     \
            int c = tid + 512 * u;                                                        \
            a_r[u] = *(const float4*)(X + (size_t)(m_blk + (c >> 3)) * DD + kof + (c & 7) * 4); \
        }                                                                                 \
        _Pragma("unroll")                                                                 \
        for (int u = 0; u < 4; ++u) {                                                     \
            int c = tid + 512 * u;                                                        \
            b_r[u] = *(const float4*)(W + (size_t)(c >> 3) * DD + kof + (c & 7) * 4);     \
        }                                                                                 \
    } while (0)

    LOAD_TILE(0);

    for (int kc = 0; kc < NKC; ++kc) {
        const int p = kc & 1;
        // stage current regs -> LDS[p] (bf16)
#pragma unroll
        for (int u = 0; u < 2; ++u) {
            int c = tid + 512 * u;
            *(unsigned long long*)&As[p][(c >> 3) * LDA + (c & 7) * 4] = pack4bf16(a_r[u]);
        }
#pragma unroll
        for (int u = 0; u < 4; ++u) {
            int c = tid + 512 * u;
            *(unsigned long long*)&Bs[p][(c >> 3) * LDB + (c & 7) * 4] = pack4bf16(b_r[u]);
        }
        // prefetch next tile (consumed next iteration, after the next barrier)
        if (kc + 1 < NKC) LOAD_TILE(kc + 1);
        __syncthreads();

        // LDS -> fragments (two b64 reads each: 80B rows are 8B-aligned)
        short8 af[4], bf[4];
#pragma unroll
        for (int i = 0; i < 4; ++i) {
            const unsigned short* pa = &As[p][(wm * 64 + i * 16 + cn) * LDA + q * 8];
            ((short4v*)&af[i])[0] = *(const short4v*)pa;
            ((short4v*)&af[i])[1] = *(const short4v*)(pa + 4);
        }
#pragma unroll
        for (int j = 0; j < 4; ++j) {
            const unsigned short* pb = &Bs[p][(wn * 64 + j * 16 + cn) * LDB + q * 8];
            ((short4v*)&bf[j])[0] = *(const short4v*)pb;
            ((short4v*)&bf[j])[1] = *(const short4v*)(pb + 4);
        }

#pragma unroll
        for (int i = 0; i < 4; ++i)
#pragma unroll
            for (int j = 0; j < 4; ++j)
                acc[i][j] = __builtin_amdgcn_mfma_f32_16x16x32_bf16(af[i], bf[j], acc[i][j], 0, 0, 0);
    }

    // epilogue: C/D layout col = lane&15 (n), row = quad*4 + reg (m)
#pragma unroll
    for (int j = 0; j < 4; ++j) {
        const int n   = wn * 64 + j * 16 + cn;
        const float bvv = bias_s[n];
#pragma unroll
        for (int i = 0; i < 4; ++i) {
            const int m0 = m_blk + wm * 64 + i * 16 + q * 4;
#pragma unroll
            for (int r = 0; r < 4; ++r)
                XP[(size_t)(m0 + r) * NG + n] = acc[i][j][r] + bvv;
        }
    }
#undef LOAD_TILE
}

// ---------------------------------------------------------------------------
// Phase 2: LSTM recurrence. 1 batch/block, thread = gate, wave = gate type.
// h replicated per wave (lane j holds h_j); matvec = readlane broadcast into
// FOUR independent FMA chains (the single 64-deep chain was the R2 stall).
// Gate exchange via double-buffered LDS, one barrier per step.
// ---------------------------------------------------------------------------
__global__ __launch_bounds__(256) void lstm_rec(
    const float* __restrict__ XP,   // [BB, TT, NG]
    const float* __restrict__ Whh,  // [NG, HH]
    float* __restrict__ pooled)     // [BB, HH]
{
    const int b   = blockIdx.x;
    const int tid = threadIdx.x;
    const int wv  = tid >> 6;
    const int j   = tid & 63;

    float wrow[HH];
#pragma unroll
    for (int u = 0; u < HH / 4; ++u)
        ((float4*)wrow)[u] = ((const float4*)(Whh + (size_t)tid * HH))[u];

    __shared__ float gbuf[2][NG];

    float h = 0.f, c = 0.f, hsum = 0.f;
    const float* xp = XP + (size_t)b * TT * NG + tid;

    // prefetch ring depth 4; wraps at the end (dead loads, valid addresses)
    float xr[4];
#pragma unroll
    for (int u = 0; u < 4; ++u) xr[u] = xp[(size_t)u * NG];

    for (int t0 = 0; t0 < TT; t0 += 4) {
#pragma unroll
        for (int u = 0; u < 4; ++u) {
            const int t = t0 + u;
            float a0 = xr[u], a1 = 0.f, a2 = 0.f, a3 = 0.f;
            xr[u] = xp[(size_t)((t + 4) & (TT - 1)) * NG];

            const int hb = __float_as_int(h);
#pragma unroll
            for (int kb = 0; kb < HH; kb += 4) {
                float h0 = __int_as_float(__builtin_amdgcn_readlane(hb, kb + 0));
                float h1 = __int_as_float(__builtin_amdgcn_readlane(hb, kb + 1));
                float h2 = __int_as_float(__builtin_amdgcn_readlane(hb, kb + 2));
                float h3 = __int_as_float(__builtin_amdgcn_readlane(hb, kb + 3));
                a0 = fmaf(wrow[kb + 0], h0, a0);
                a1 = fmaf(wrow[kb + 1], h1, a1);
                a2 = fmaf(wrow[kb + 2], h2, a2);
                a3 = fmaf(wrow[kb + 3], h3, a3);
            }
            const float acc = (a0 + a1) + (a2 + a3);

            float a;
            if (wv == 2) {                          // tanh gate (wave-uniform)
                a = 2.f / (1.f + __expf(-2.f * acc)) - 1.f;
            } else {                                // sigmoid gates
                a = 1.f / (1.f + __expf(-acc));
            }
            const int p = t & 1;
            gbuf[p][tid] = a;
            __syncthreads();
            const float iv = gbuf[p][j];
            const float fv = gbuf[p][64 + j];
            const float gv = gbuf[p][128 + j];
            const float ov = gbuf[p][192 + j];
            c = fmaf(fv, c, iv * gv);
            const float th = 2.f / (1.f + __expf(-2.f * c)) - 1.f;
            h = ov * th;
            hsum += h;
        }
    }

    if (tid < HH) pooled[(size_t)b * HH + j] = hsum * (1.f / (float)TT);
}

// ---------------------------------------------------------------------------
// Phase 3: MLP head + softmax. One block, one thread per batch row.
// ---------------------------------------------------------------------------
__global__ __launch_bounds__(256) void head_kernel(
    const float* __restrict__ pooled,  // [BB, HH]
    const float* __restrict__ W1,      // [32, HH]
    const float* __restrict__ b1,      // [32]
    const float* __restrict__ W2,      // [3, 32]
    const float* __restrict__ b2,      // [3]
    float* __restrict__ out)           // [BB, 3]
{
    __shared__ float W1s[32 * HH];
    __shared__ float W2s[3 * 32];
    __shared__ float b1s[32];
    __shared__ float b2s[3];

    const int tid = threadIdx.x;
    for (int i = tid; i < 32 * HH; i += 256) W1s[i] = W1[i];
    if (tid < 96) W2s[tid] = W2[tid];
    if (tid < 32) b1s[tid] = b1[tid];
    if (tid < 3)  b2s[tid] = b2[tid];
    __syncthreads();

    float p[HH];
    const float4* p4 = (const float4*)(pooled + (size_t)tid * HH);
#pragma unroll
    for (int q = 0; q < HH / 4; ++q) ((float4*)p)[q] = p4[q];

    float hbuf[32];
#pragma unroll
    for (int k = 0; k < 32; ++k) {
        float s = b1s[k];
        const float* wr = &W1s[k * HH];
#pragma unroll
        for (int jj = 0; jj < HH; ++jj) s += p[jj] * wr[jj];
        hbuf[k] = s > 0.f ? s : 0.f;
    }

    float lg[3];
#pragma unroll
    for (int cc = 0; cc < 3; ++cc) {
        float s = b2s[cc];
        const float* wr = &W2s[cc * 32];
#pragma unroll
        for (int k = 0; k < 32; ++k) s += hbuf[k] * wr[k];
        lg[cc] = s;
    }

    float mx = fmaxf(lg[0], fmaxf(lg[1], lg[2]));
    float e0 = __expf(lg[0] - mx);
    float e1 = __expf(lg[1] - mx);
    float e2 = __expf(lg[2] - mx);
    float inv = 1.f / (e0 + e1 + e2);
    out[tid * 3 + 0] = e0 * inv;
    out[tid * 3 + 1] = e1 * inv;
    out[tid * 3 + 2] = e2 * inv;
}

// ---------------------------------------------------------------------------
extern "C" void kernel_launch(void* const* d_in, const int* in_sizes, int n_in,
                              void* d_out, int out_size, void* d_ws, size_t ws_size,
                              hipStream_t stream) {
    const float* x    = (const float*)d_in[0];  // [256,512,512]
    const float* W_ih = (const float*)d_in[1];  // [256,512]
    const float* W_hh = (const float*)d_in[2];  // [256,64]
    const float* b_ih = (const float*)d_in[3];  // [256]
    const float* b_hh = (const float*)d_in[4];  // [256]
    const float* W1   = (const float*)d_in[5];  // [32,64]
    const float* b1   = (const float*)d_in[6];  // [32]
    const float* W2   = (const float*)d_in[7];  // [3,32]
    const float* b2   = (const float*)d_in[8];  // [3]
    float* out = (float*)d_out;

    // workspace layout: XP [MM*NG] fp32 (128 MiB), then pooled [BB*HH]
    float* XP     = (float*)d_ws;
    float* pooled = XP + (size_t)MM * NG;

    gemm_xproj<<<dim3(MM / BM), 512, 0, stream>>>(x, W_ih, b_ih, b_hh, XP);
    lstm_rec<<<dim3(BB), 256, 0, stream>>>(XP, W_hh, pooled);
    head_kernel<<<dim3(1), 256, 0, stream>>>(pooled, W1, b1, W2, b2, out);
}